// Round 4
// baseline (126.709 us; speedup 1.0000x reference)
//
#include <hip/hip_runtime.h>

#define IN_DIM  4096
#define OUT_DIM 11008
#define NSUB    1376
#define KSQ     256
#define DSUB    8
#define BATCH   32

#define DTILE   8                    // subspaces per block -> N tile = 64
#define NTILE   64
#define KC      128                  // k elements staged per chunk
#define KSPLIT  8                    // k-blocks in grid
#define KPB     (IN_DIM / KSPLIT)    // 512 k per block
#define NCHUNK  (KPB / KC)           // 4 chunks per block
#define NBLK    (OUT_DIM / NTILE)    // 172

typedef unsigned short ushort_t;
typedef unsigned int   uint_t;
typedef unsigned char  u8;
typedef __attribute__((ext_vector_type(8))) short bf16x8;
typedef __attribute__((ext_vector_type(4))) float f32x4;

// LDS strides (elements). 136 = 68 dwords (≡4 mod 32 banks): balanced b128 access.
#define SW_STRIDE 136
#define SX_STRIDE 136

// workspace layout (bytes)
#define VEC_N    (NSUB * KSQ * DSUB)          // 2818048 floats
#define XBF_OFF  (VEC_N * 2)                  // 5636096
#define IDX_OFF  (XBF_OFF + BATCH * IN_DIM * 2)   // 5898240... (xbf = 262144 B)
#define PREP_V   (VEC_N / 2)                  // 1409024 uint (2 bf16 each)
#define PREP_X   (BATCH * IN_DIM / 2)         // 65536
#define PREP_O   (BATCH * OUT_DIM)            // 352256
#define PREP_N   (PREP_V + PREP_X + PREP_O)   // 1826816 = 7136 * 256

__device__ __forceinline__ ushort_t f2bf(float f) {
    union { float f; uint_t u; } a; a.f = f;
    uint_t u = a.u;
    u += 0x7fffu + ((u >> 16) & 1u);   // round-to-nearest-even
    return (ushort_t)(u >> 16);
}

__global__ __launch_bounds__(256) void pq_prep(
    const float* __restrict__ x, const float* __restrict__ vecs,
    const float* __restrict__ bias,
    uint_t* __restrict__ vbf, uint_t* __restrict__ xbf, float* __restrict__ out)
{
    int tid = blockIdx.x * 256 + threadIdx.x;
    if (tid < PREP_V) {
        float2 v = ((const float2*)vecs)[tid];
        vbf[tid] = (uint_t)f2bf(v.x) | ((uint_t)f2bf(v.y) << 16);
    } else if (tid < PREP_V + PREP_X) {
        int i = tid - PREP_V;
        float2 v = ((const float2*)x)[i];
        xbf[i] = (uint_t)f2bf(v.x) | ((uint_t)f2bf(v.y) << 16);
    } else {
        int i = tid - (PREP_V + PREP_X);
        out[i] = bias[i % OUT_DIM];
    }
}

// Transpose idx[i][d] (int32) -> idxT8[d][i] (u8). Tile 32d x 256i via LDS.
__global__ __launch_bounds__(256) void pq_tr(
    const int* __restrict__ idx, u8* __restrict__ idxT)
{
    __shared__ u8 sT[32 * 260];     // stride 260: (65 dwords ≡ 1 mod 32 banks)
    const int i0  = blockIdx.x * 256;     // 16 i-tiles
    const int d0t = blockIdx.y * 32;      // 43 d-tiles
    const int dd = threadIdx.x & 31;
    const int ib = threadIdx.x >> 5;      // 0..7
    #pragma unroll 8
    for (int ii = 0; ii < 32; ++ii) {
        int il = ii * 8 + ib;
        sT[dd * 260 + il] = (u8)idx[(size_t)(i0 + il) * NSUB + d0t + dd];
    }
    __syncthreads();
    const int l  = threadIdx.x & 63;
    const int w4 = threadIdx.x >> 6;      // 4 rows in parallel
    #pragma unroll
    for (int rr = 0; rr < 8; ++rr) {
        int row = rr * 4 + w4;
        uint_t v = *(const uint_t*)&sT[row * 260 + l * 4];
        *(uint_t*)&idxT[(size_t)(d0t + row) * IN_DIM + i0 + l * 4] = v;
    }
}

__global__ __launch_bounds__(256) void pq_main(
    const ushort_t* __restrict__ xbf, const uint4* __restrict__ vbf,
    const u8* __restrict__ idxT, float* __restrict__ out)
{
    __shared__ ushort_t sW[NTILE * SW_STRIDE];  // 17.4 KB: W^T tile [n][k]
    __shared__ ushort_t sX[BATCH * SX_STRIDE];  // 8.7 KB: x tile [m][k]

    const int t    = threadIdx.x;
    const int nblk = blockIdx.x;        // 0..171
    const int kblk = blockIdx.y;        // 0..7
    const int d0   = nblk * DTILE;
    const int kbase = kblk * KPB;

    const int wave = t >> 6;
    const int lane = t & 63;
    const int l15  = lane & 15;
    const int l4   = lane >> 4;

    const int gd = t >> 5;              // gather: subspace 0..7
    const int go = t & 31;              // gather: k-quad 0..31

    f32x4 acc[2];
    acc[0] = (f32x4)0.0f;
    acc[1] = (f32x4)0.0f;

    // prologue: chunk 0's idx codes (sequential u8) + x into registers
    uint_t iregC, iregN = 0;
    uint4  xregC[2], xregN[2];
    iregC = *(const uint_t*)&idxT[(size_t)(d0 + gd) * IN_DIM + kbase + go * 4];
    #pragma unroll
    for (int p = 0; p < 2; ++p) {
        int f = p * 256 + t, b = f >> 4, qx = f & 15;
        xregC[p] = ((const uint4*)xbf)[b * (IN_DIM / 8) + kbase / 8 + qx];
    }

    #pragma unroll
    for (int c = 0; c < NCHUNK; ++c) {
        // --- gather 4 bf16 codewords (codes already in registers)
        const uint4* vb = vbf + (size_t)(d0 + gd) * KSQ;
        uint4 q0 = vb[iregC & 255];
        uint4 q1 = vb[(iregC >> 8) & 255];
        uint4 q2 = vb[(iregC >> 16) & 255];
        uint4 q3 = vb[iregC >> 24];

        // --- prefetch next chunk's idx + x (issued after gathers: no extra wait)
        if (c + 1 < NCHUNK) {
            const int i0n = kbase + (c + 1) * KC;
            iregN = *(const uint_t*)&idxT[(size_t)(d0 + gd) * IN_DIM + i0n + go * 4];
            #pragma unroll
            for (int p = 0; p < 2; ++p) {
                int f = p * 256 + t, b = f >> 4, qx = f & 15;
                xregN[p] = ((const uint4*)xbf)[b * (IN_DIM / 8) + i0n / 8 + qx];
            }
        }

        // --- 4x8 bf16 transpose via v_perm (waits only on q0..q3)
        uint2 wv[8];
        #pragma unroll
        for (int j = 0; j < 8; ++j) {
            const uint_t sel = (j & 1) ? 0x07060302u : 0x05040100u;
            const int cc = j >> 1;
            uint_t c0 = cc == 0 ? q0.x : cc == 1 ? q0.y : cc == 2 ? q0.z : q0.w;
            uint_t c1 = cc == 0 ? q1.x : cc == 1 ? q1.y : cc == 2 ? q1.z : q1.w;
            uint_t c2 = cc == 0 ? q2.x : cc == 1 ? q2.y : cc == 2 ? q2.z : q2.w;
            uint_t c3 = cc == 0 ? q3.x : cc == 1 ? q3.y : cc == 2 ? q3.z : q3.w;
            wv[j].x = __builtin_amdgcn_perm(c1, c0, sel);
            wv[j].y = __builtin_amdgcn_perm(c3, c2, sel);
        }

        __syncthreads();   // prior chunk's MFMA reads of sW/sX complete

        // --- commit: x tile + transposed W tile into LDS
        #pragma unroll
        for (int p = 0; p < 2; ++p) {
            int f = p * 256 + t, b = f >> 4, qx = f & 15;
            *(uint4*)&sX[b * SX_STRIDE + qx * 8] = xregC[p];
        }
        #pragma unroll
        for (int j = 0; j < 8; ++j)
            *(uint2*)&sW[(gd * 8 + j) * SW_STRIDE + go * 4] = wv[j];

        __syncthreads();   // tiles visible

        // --- MFMA over this chunk: wave owns 16 cols, full M=32
        #pragma unroll
        for (int kq = 0; kq < KC / 32; ++kq) {
            bf16x8 A0 = *(const bf16x8*)&sX[(l15) * SX_STRIDE + kq * 32 + l4 * 8];
            bf16x8 A1 = *(const bf16x8*)&sX[(16 + l15) * SX_STRIDE + kq * 32 + l4 * 8];
            bf16x8 B  = *(const bf16x8*)&sW[(wave * 16 + l15) * SW_STRIDE + kq * 32 + l4 * 8];
            acc[0] = __builtin_amdgcn_mfma_f32_16x16x32_bf16(A0, B, acc[0], 0, 0, 0);
            acc[1] = __builtin_amdgcn_mfma_f32_16x16x32_bf16(A1, B, acc[1], 0, 0, 0);
        }

        iregC = iregN;
        xregC[0] = xregN[0];
        xregC[1] = xregN[1];
    }

    // --- epilogue: accumulate into out (pre-initialized with bias); 8/address
    #pragma unroll
    for (int mt = 0; mt < 2; ++mt)
        #pragma unroll
        for (int r = 0; r < 4; ++r) {
            int row = mt * 16 + l4 * 4 + r;                 // batch
            int col = nblk * NTILE + wave * 16 + l15;       // out col
            atomicAdd(&out[(size_t)row * OUT_DIM + col], acc[mt][r]);
        }
}

extern "C" void kernel_launch(void* const* d_in, const int* in_sizes, int n_in,
                              void* d_out, int out_size, void* d_ws, size_t ws_size,
                              hipStream_t stream) {
    const float* x    = (const float*)d_in[0];
    const float* vecs = (const float*)d_in[1];
    const float* bias = (const float*)d_in[2];
    const int*   idx  = (const int*)d_in[3];
    float* out = (float*)d_out;

    uint_t* vbf   = (uint_t*)d_ws;                         // 5.6 MB bf16 codebook
    uint_t* xbf   = (uint_t*)((char*)d_ws + XBF_OFF);      // 256 KB bf16 x
    u8*     idxT8 = (u8*)((char*)d_ws + IDX_OFF);          // 5.6 MB u8 idx^T

    pq_prep<<<PREP_N / 256, 256, 0, stream>>>(x, vecs, bias, vbf, xbf, out);
    dim3 tgrid(IN_DIM / 256, NSUB / 32);                   // (16, 43)
    pq_tr<<<tgrid, 256, 0, stream>>>(idx, idxT8);
    dim3 grid(NBLK, KSPLIT);
    pq_main<<<grid, 256, 0, stream>>>((const ushort_t*)xbf, (const uint4*)vbf,
                                      idxT8, out);
}

// Round 5
// 120.743 us; speedup vs baseline: 1.0494x; 1.0494x over previous
//
#include <hip/hip_runtime.h>

#define IN_DIM  4096
#define OUT_DIM 11008
#define NSUB    1376
#define KSQ     256
#define DSUB    8
#define BATCH   32

#define KSPLIT  8
#define KPB     (IN_DIM / KSPLIT)    // 512 k per block
#define NSTEP   (KPB / 32)           // 16 k-steps per wave
#define NBLK    (OUT_DIM / 64)       // 172 (block = 4 waves x 16 cols)

typedef unsigned short ushort_t;
typedef unsigned int   uint_t;
typedef unsigned char  u8;
typedef __attribute__((ext_vector_type(8))) short bf16x8;
typedef __attribute__((ext_vector_type(4))) float f32x4;

// workspace layout (bytes)
#define VEC_N    (NSUB * KSQ * DSUB)              // 2818048 floats
#define XBF_OFF  (VEC_N * 2)                      // 5636096
#define IDX_OFF  (XBF_OFF + BATCH * IN_DIM * 2)
#define PREP_V   (VEC_N / 2)                      // 1409024
#define PREP_X   (BATCH * IN_DIM / 2)             // 65536
#define PREP_O   (BATCH * OUT_DIM)                // 352256
#define PREP_N   (PREP_V + PREP_X + PREP_O)       // 1826816 = 7136 * 256
#define PREP_B   (PREP_N / 256)                   // 7136 blocks
#define TR_B     ((IN_DIM / 256) * (NSUB / 32))   // 16 * 43 = 688 blocks

__device__ __forceinline__ ushort_t f2bf(float f) {
    union { float f; uint_t u; } a; a.f = f;
    uint_t u = a.u;
    u += 0x7fffu + ((u >> 16) & 1u);   // round-to-nearest-even
    return (ushort_t)(u >> 16);
}

// Fused: bf16-cast of vectors & x, out=bias init, and idx int32 -> u8 transpose.
__global__ __launch_bounds__(256) void pq_prep(
    const float* __restrict__ x, const float* __restrict__ vecs,
    const float* __restrict__ bias, const int* __restrict__ idx,
    uint_t* __restrict__ vbf, uint_t* __restrict__ xbf,
    u8* __restrict__ idxT, float* __restrict__ out)
{
    __shared__ u8 sT[32 * 260];
    const int bx = blockIdx.x;
    if (bx < PREP_B) {
        int tid = bx * 256 + threadIdx.x;
        if (tid < PREP_V) {
            float2 v = ((const float2*)vecs)[tid];
            vbf[tid] = (uint_t)f2bf(v.x) | ((uint_t)f2bf(v.y) << 16);
        } else if (tid < PREP_V + PREP_X) {
            int i = tid - PREP_V;
            float2 v = ((const float2*)x)[i];
            xbf[i] = (uint_t)f2bf(v.x) | ((uint_t)f2bf(v.y) << 16);
        } else {
            int i = tid - (PREP_V + PREP_X);
            out[i] = bias[i % OUT_DIM];
        }
    } else {
        // transpose tile: 32 d x 256 i
        const int b2  = bx - PREP_B;
        const int i0  = (b2 & 15) * 256;
        const int d0t = (b2 >> 4) * 32;
        const int dd = threadIdx.x & 31;
        const int ib = threadIdx.x >> 5;
        #pragma unroll 8
        for (int ii = 0; ii < 32; ++ii) {
            int il = ii * 8 + ib;
            sT[dd * 260 + il] = (u8)idx[(size_t)(i0 + il) * NSUB + d0t + dd];
        }
        __syncthreads();
        const int l  = threadIdx.x & 63;
        const int w4 = threadIdx.x >> 6;
        #pragma unroll
        for (int rr = 0; rr < 8; ++rr) {
            int row = rr * 4 + w4;
            uint_t v = *(const uint_t*)&sT[row * 260 + l * 4];
            *(uint_t*)&idxT[(size_t)(d0t + row) * IN_DIM + i0 + l * 4] = v;
        }
    }
}

// Barrier-free wave-autonomous GEMM. Wave owns 16 cols x KPB k.
// Lane (n=l&15, oct=l>>4): gathers codeword for k=k0+oct*8+(n&7), d=d0w+(n>>3);
// 8-lane group transposes via wave-private LDS (lgkmcnt ordering, no barrier).
__global__ __launch_bounds__(256, 6) void pq_main(
    const ushort_t* __restrict__ xbf, const uint4* __restrict__ vbf,
    const u8* __restrict__ idxT, float* __restrict__ out)
{
    __shared__ uint4 sScr[4 * 64];     // 4 KB: per-wave 64-slot scratch

    const int t    = threadIdx.x;
    const int wave = t >> 6;
    const int lane = t & 63;
    const int n    = lane & 15;
    const int oct  = lane >> 4;
    const int jn   = n & 7;
    const int dloc = n >> 3;

    const int nblk  = blockIdx.x;          // 0..171
    const int kblk  = blockIdx.y;          // 0..7
    const int kbase = kblk * KPB;
    const int d     = nblk * 8 + wave * 2 + dloc;

    const uint4*    vb = vbf + (size_t)d * KSQ;
    const u8*       ip = idxT + (size_t)d * IN_DIM + kbase + oct * 8 + jn;
    const ushort_t* xr = xbf + kbase + oct * 8;

    uint4*        wslot = &sScr[wave * 64 + lane];
    const uint_t* sc    = (const uint_t*)&sScr[wave * 64 + (lane & ~7)];
    const int     w     = jn >> 1;
    const uint_t  sel   = (jn & 1) ? 0x07060302u : 0x05040100u;

    f32x4 acc0 = (f32x4)0.0f;
    f32x4 acc1 = (f32x4)0.0f;

    uint_t code = ip[0];                   // step-0 code prefetch

    #pragma unroll 4
    for (int s = 0; s < NSTEP; ++s) {
        // gather this step's codeword; prefetch next step's code
        uint4 q = vb[code];
        if (s + 1 < NSTEP) code = ip[(s + 1) * 32];

        // A fragments straight from L2-resident bf16 x
        bf16x8 A0 = *(const bf16x8*)(xr + (size_t)n * IN_DIM + s * 32);
        bf16x8 A1 = *(const bf16x8*)(xr + (size_t)(16 + n) * IN_DIM + s * 32);

        // wave-private LDS transpose (no barrier; lgkmcnt orders write->read)
        *wslot = q;
        uint_t r0 = sc[0 * 4 + w], r1 = sc[1 * 4 + w];
        uint_t r2 = sc[2 * 4 + w], r3 = sc[3 * 4 + w];
        uint_t r4 = sc[4 * 4 + w], r5 = sc[5 * 4 + w];
        uint_t r6 = sc[6 * 4 + w], r7 = sc[7 * 4 + w];

        union { uint_t u[4]; bf16x8 v; } B;
        B.u[0] = __builtin_amdgcn_perm(r1, r0, sel);
        B.u[1] = __builtin_amdgcn_perm(r3, r2, sel);
        B.u[2] = __builtin_amdgcn_perm(r5, r4, sel);
        B.u[3] = __builtin_amdgcn_perm(r7, r6, sel);

        acc0 = __builtin_amdgcn_mfma_f32_16x16x32_bf16(A0, B.v, acc0, 0, 0, 0);
        acc1 = __builtin_amdgcn_mfma_f32_16x16x32_bf16(A1, B.v, acc1, 0, 0, 0);
    }

    // epilogue: accumulate into out (pre-initialized with bias); 8/address
    const int col = nblk * 64 + wave * 16 + n;
    #pragma unroll
    for (int r = 0; r < 4; ++r) {
        int row = oct * 4 + r;
        atomicAdd(&out[(size_t)row * OUT_DIM + col], acc0[r]);
        atomicAdd(&out[(size_t)(16 + row) * OUT_DIM + col], acc1[r]);
    }
}

extern "C" void kernel_launch(void* const* d_in, const int* in_sizes, int n_in,
                              void* d_out, int out_size, void* d_ws, size_t ws_size,
                              hipStream_t stream) {
    const float* x    = (const float*)d_in[0];
    const float* vecs = (const float*)d_in[1];
    const float* bias = (const float*)d_in[2];
    const int*   idx  = (const int*)d_in[3];
    float* out = (float*)d_out;

    uint_t* vbf   = (uint_t*)d_ws;                         // 5.6 MB bf16 codebook
    uint_t* xbf   = (uint_t*)((char*)d_ws + XBF_OFF);      // 256 KB bf16 x
    u8*     idxT8 = (u8*)((char*)d_ws + IDX_OFF);          // 5.6 MB u8 idx^T

    pq_prep<<<PREP_B + TR_B, 256, 0, stream>>>(x, vecs, bias, idx,
                                               vbf, xbf, idxT8, out);
    dim3 grid(NBLK, KSPLIT);
    pq_main<<<grid, 256, 0, stream>>>((const ushort_t*)xbf, (const uint4*)vbf,
                                      idxT8, out);
}

// Round 6
// 120.487 us; speedup vs baseline: 1.0516x; 1.0021x over previous
//
#include <hip/hip_runtime.h>

#define IN_DIM  4096
#define OUT_DIM 11008
#define NSUB    1376
#define KSQ     256
#define DSUB    8
#define BATCH   32

#define KSPLIT  8
#define KPB     (IN_DIM / KSPLIT)    // 512 k per block
#define NSTEP   (KPB / 32)           // 16 k-steps per wave
#define NBLK    (OUT_DIM / 64)       // 172 (block = 4 waves x 16 cols)
#define GRID_MAIN (NBLK * KSPLIT)    // 1376

typedef unsigned short ushort_t;
typedef unsigned int   uint_t;
typedef unsigned char  u8;
typedef __attribute__((ext_vector_type(8))) short bf16x8;
typedef __attribute__((ext_vector_type(4))) float f32x4;

// workspace layout (bytes)
#define VEC_N    (NSUB * KSQ * DSUB)              // 2818048 floats
#define XBF_OFF  (VEC_N * 2)                      // 5636096
#define IDX_OFF  (XBF_OFF + BATCH * IN_DIM * 2)   // 5898240
#define PART_OFF (IDX_OFF + NSUB * IN_DIM)        // 11534336
#define PREP_V   (VEC_N / 2)                      // 1409024
#define PREP_X   (BATCH * IN_DIM / 2)             // 65536
#define PREP_N   (PREP_V + PREP_X)                // 1474560 = 5760 * 256
#define PREP_B   (PREP_N / 256)                   // 5760
#define TR_B     ((IN_DIM / 256) * (NSUB / 32))   // 688

__device__ __forceinline__ ushort_t f2bf(float f) {
    union { float f; uint_t u; } a; a.f = f;
    uint_t u = a.u;
    u += 0x7fffu + ((u >> 16) & 1u);   // round-to-nearest-even
    return (ushort_t)(u >> 16);
}

// Fused: bf16-cast of vectors & x, and idx int32 -> u8 transpose.
__global__ __launch_bounds__(256) void pq_prep(
    const float* __restrict__ x, const float* __restrict__ vecs,
    const int* __restrict__ idx,
    uint_t* __restrict__ vbf, uint_t* __restrict__ xbf, u8* __restrict__ idxT)
{
    __shared__ u8 sT[32 * 260];
    const int bx = blockIdx.x;
    if (bx < PREP_B) {
        int tid = bx * 256 + threadIdx.x;
        if (tid < PREP_V) {
            float2 v = ((const float2*)vecs)[tid];
            vbf[tid] = (uint_t)f2bf(v.x) | ((uint_t)f2bf(v.y) << 16);
        } else {
            int i = tid - PREP_V;
            float2 v = ((const float2*)x)[i];
            xbf[i] = (uint_t)f2bf(v.x) | ((uint_t)f2bf(v.y) << 16);
        }
    } else {
        // transpose tile: 32 d x 256 i
        const int b2  = bx - PREP_B;
        const int i0  = (b2 & 15) * 256;
        const int d0t = (b2 >> 4) * 32;
        const int dd = threadIdx.x & 31;
        const int ib = threadIdx.x >> 5;
        #pragma unroll 8
        for (int ii = 0; ii < 32; ++ii) {
            int il = ii * 8 + ib;
            sT[dd * 260 + il] = (u8)idx[(size_t)(i0 + il) * NSUB + d0t + dd];
        }
        __syncthreads();
        const int l  = threadIdx.x & 63;
        const int w4 = threadIdx.x >> 6;
        #pragma unroll
        for (int rr = 0; rr < 8; ++rr) {
            int row = rr * 4 + w4;
            uint_t v = *(const uint_t*)&sT[row * 260 + l * 4];
            *(uint_t*)&idxT[(size_t)(d0t + row) * IN_DIM + i0 + l * 4] = v;
        }
    }
}

// Barrier-free wave-autonomous GEMM, software-pipelined.
// Wave owns 16 cols x KPB k. Per 32-k step each lane gathers one bf16
// codeword; 8-lane groups transpose via wave-private LDS with a DIAGONAL
// slot permutation (slot=(jn+grp)&7) so transpose reads are bank-conflict-free.
__global__ __launch_bounds__(256, 4) void pq_main(
    const ushort_t* __restrict__ xbf, const uint4* __restrict__ vbf,
    const u8* __restrict__ idxT, float* __restrict__ part)
{
    __shared__ uint4 sScr[2][4][64];   // [parity][wave][slot], 8 KB

    const int t    = threadIdx.x;
    const int wave = t >> 6;
    const int lane = t & 63;
    const int n    = lane & 15;
    const int oct  = lane >> 4;
    const int jn   = n & 7;
    const int dloc = n >> 3;
    const int grp  = lane >> 3;              // oct*2 + dloc
    const int w    = jn >> 1;
    const uint_t sel = (jn & 1) ? 0x07060302u : 0x05040100u;

    // XCD-affine decode: same-nblk k-siblings get the same blockIdx%8.
    int id = blockIdx.x;
    int nblk, kblk;
    if (id < 1344) {
        int r = id & 7, q = id >> 3;         // q in [0,168)
        nblk = r + 8 * (q % 21);
        kblk = q / 21;
    } else {
        int id2 = id - 1344;                 // 32 leftover blocks
        nblk = 168 + (id2 & 3);
        kblk = id2 >> 2;
    }

    const int kbase = kblk * KPB;
    const int d     = nblk * 8 + wave * 2 + dloc;

    const uint4*    vb = vbf + (size_t)d * KSQ;
    const u8*       ip = idxT + (size_t)d * IN_DIM + kbase + oct * 8 + jn;
    const ushort_t* xr = xbf + kbase + oct * 8;

    const int slot = grp * 8 + ((jn + grp) & 7);
    uint4* wr[2] = { &sScr[0][wave][slot], &sScr[1][wave][slot] };
    const uint_t* rb[2] = { (const uint_t*)&sScr[0][wave][grp * 8],
                            (const uint_t*)&sScr[1][wave][grp * 8] };

    f32x4 acc0 = (f32x4)0.0f, acc1 = (f32x4)0.0f;

    // pipeline prologue: codes depth-4, gathers depth-2, A depth-1
    uint_t code[4];
    code[0] = ip[0];
    code[1] = ip[32];
    code[2] = ip[64];
    code[3] = ip[96];
    uint4 qreg[2];
    qreg[0] = vb[code[0]];
    qreg[1] = vb[code[1]];
    bf16x8 A0[2], A1[2];
    A0[0] = *(const bf16x8*)(xr + (size_t)n * IN_DIM);
    A1[0] = *(const bf16x8*)(xr + (size_t)(16 + n) * IN_DIM);

    #pragma unroll
    for (int s = 0; s < NSTEP; ++s) {
        const int p = s & 1;

        *wr[p] = qreg[p];                              // ds_write_b128 (contig 1KB)
        if (s + 2 < NSTEP) qreg[p] = vb[code[(s + 2) & 3]];
        if (s + 4 < NSTEP) code[s & 3] = ip[(s + 4) * 32];
        if (s + 1 < NSTEP) {
            A0[(s + 1) & 1] = *(const bf16x8*)(xr + (size_t)n * IN_DIM + (s + 1) * 32);
            A1[(s + 1) & 1] = *(const bf16x8*)(xr + (size_t)(16 + n) * IN_DIM + (s + 1) * 32);
        }

        // conflict-free diagonal reads: bank = 4*((g+grp)&7)+w, bijective
        const uint_t* r = rb[p];
        uint_t r0 = r[((0 + grp) & 7) * 4 + w];
        uint_t r1 = r[((1 + grp) & 7) * 4 + w];
        uint_t r2 = r[((2 + grp) & 7) * 4 + w];
        uint_t r3 = r[((3 + grp) & 7) * 4 + w];
        uint_t r4 = r[((4 + grp) & 7) * 4 + w];
        uint_t r5 = r[((5 + grp) & 7) * 4 + w];
        uint_t r6 = r[((6 + grp) & 7) * 4 + w];
        uint_t r7 = r[((7 + grp) & 7) * 4 + w];

        union { uint_t u[4]; bf16x8 v; } B;
        B.u[0] = __builtin_amdgcn_perm(r1, r0, sel);
        B.u[1] = __builtin_amdgcn_perm(r3, r2, sel);
        B.u[2] = __builtin_amdgcn_perm(r5, r4, sel);
        B.u[3] = __builtin_amdgcn_perm(r7, r6, sel);

        acc0 = __builtin_amdgcn_mfma_f32_16x16x32_bf16(A0[p], B.v, acc0, 0, 0, 0);
        acc1 = __builtin_amdgcn_mfma_f32_16x16x32_bf16(A1[p], B.v, acc1, 0, 0, 0);
    }

    // epilogue: plain stores to split-K partials (no atomics)
    float* pp = part + (size_t)kblk * (BATCH * OUT_DIM);
    const int col = nblk * 64 + wave * 16 + n;
    #pragma unroll
    for (int r = 0; r < 4; ++r) {
        int row = oct * 4 + r;
        pp[(size_t)row * OUT_DIM + col] = acc0[r];
        pp[(size_t)(16 + row) * OUT_DIM + col] = acc1[r];
    }
}

__global__ __launch_bounds__(256) void pq_reduce(
    const float* __restrict__ part, const float* __restrict__ bias,
    float* __restrict__ out)
{
    const int bx  = blockIdx.x;              // 1376 = 32 rows * 43 col-blocks
    const int row = bx / 43;
    const int cb  = bx - row * 43;
    const int col = cb * 256 + threadIdx.x;
    const size_t e = (size_t)row * OUT_DIM + col;
    float s = bias[col];
    #pragma unroll
    for (int k = 0; k < KSPLIT; ++k)
        s += part[(size_t)k * (BATCH * OUT_DIM) + e];
    out[e] = s;
}

extern "C" void kernel_launch(void* const* d_in, const int* in_sizes, int n_in,
                              void* d_out, int out_size, void* d_ws, size_t ws_size,
                              hipStream_t stream) {
    const float* x    = (const float*)d_in[0];
    const float* vecs = (const float*)d_in[1];
    const float* bias = (const float*)d_in[2];
    const int*   idx  = (const int*)d_in[3];
    float* out = (float*)d_out;

    uint_t* vbf   = (uint_t*)d_ws;                       // 5.6 MB bf16 codebook
    uint_t* xbf   = (uint_t*)((char*)d_ws + XBF_OFF);    // 256 KB bf16 x
    u8*     idxT8 = (u8*)((char*)d_ws + IDX_OFF);        // 5.6 MB u8 idx^T
    float*  part  = (float*)((char*)d_ws + PART_OFF);    // 11.3 MB fp32 partials

    pq_prep<<<PREP_B + TR_B, 256, 0, stream>>>(x, vecs, idx, vbf, xbf, idxT8);
    pq_main<<<GRID_MAIN, 256, 0, stream>>>((const ushort_t*)xbf, (const uint4*)vbf,
                                           idxT8, part);
    pq_reduce<<<BATCH * OUT_DIM / 256, 256, 0, stream>>>(part, bias, out);
}